// Round 6
// baseline (62.825 us; speedup 1.0000x reference)
//
#include <hip/hip_runtime.h>
#include <hip/hip_bf16.h>

typedef float f32x4 __attribute__((ext_vector_type(4)));
typedef int   i32x4 __attribute__((ext_vector_type(4)));
typedef int   i32x8 __attribute__((ext_vector_type(8)));

#define NC 4096
#define ND 1024
#define EPSF 1e-10f
#define NT 8        // K-tiles of BK=128 (fp8)
#define SCALE1 127  // E8M0 exponent byte for 2^0

// ---------------- fp32 -> fp8 e4m3 convert + row norms/sums; last block = mask ----------------
__global__ void convert_kernel(const float* __restrict__ F, const float* __restrict__ P,
                               unsigned char* __restrict__ Fb, unsigned char* __restrict__ Pb,
                               float* __restrict__ f2, float* __restrict__ p2,
                               float* __restrict__ psum,
                               const int* __restrict__ ann, int n_ann,
                               float* __restrict__ counts, float* __restrict__ accum) {
  int bid = blockIdx.x;
  int tid = threadIdx.x;
  if (bid == 2 * NC) {  // fused mask/zero block (no atomics: LDS bitmap)
    __shared__ unsigned char mark[NC];
    for (int i = tid; i < NC; i += 256) mark[i] = 0;
    __syncthreads();
    for (int t = tid; t < n_ann; t += 256) {
      int idx = ann[t * 5 + 4];
      if (idx >= 0 && idx < NC) mark[idx] = 1;  // benign race: all write 1
    }
    __syncthreads();
    for (int i = tid; i < NC; i += 256) counts[i] = (float)mark[i];
    if (tid < 8) accum[tid] = 0.f;   // re-zero every call (graph replay)
    return;
  }
  bool isP = bid >= NC;
  int row = isP ? bid - NC : bid;
  const float* src = (isP ? P : F) + (size_t)row * ND;
  unsigned char* dst = (isP ? Pb : Fb) + (size_t)row * ND;
  float4 v = *reinterpret_cast<const float4*>(src + tid * 4);
  int pk = __builtin_amdgcn_cvt_pk_fp8_f32(v.x, v.y, 0, false);   // bytes 0,1
  pk = __builtin_amdgcn_cvt_pk_fp8_f32(v.z, v.w, pk, true);       // bytes 2,3
  *reinterpret_cast<int*>(dst + tid * 4) = pk;
  float sq = v.x * v.x + v.y * v.y + v.z * v.z + v.w * v.w;
  float sm = v.x + v.y + v.z + v.w;
  #pragma unroll
  for (int off = 32; off; off >>= 1) {
    sq += __shfl_down(sq, off);
    sm += __shfl_down(sm, off);
  }
  __shared__ float rs[4], rm[4];
  int wid = tid >> 6, lane = tid & 63;
  if (lane == 0) { rs[wid] = sq; rm[wid] = sm; }
  __syncthreads();
  if (tid == 0) {
    float tsq = rs[0] + rs[1] + rs[2] + rs[3];
    float tsm = rm[0] + rm[1] + rm[2] + rm[3];
    if (isP) { p2[row] = tsq; psum[row] = tsm; }
    else     { f2[row] = tsq; }
  }
}

// ---------------- fused 128x128 2-phase dbuf MX-fp8 GEMM + loss reduction ----------------
#define GLDS(gsrc, ldst)                                                     \
  __builtin_amdgcn_global_load_lds(                                          \
      (__attribute__((address_space(1))) void*)(void*)(gsrc),                \
      (__attribute__((address_space(3))) void*)(void*)(ldst), 16, 0, 0)

// Stage K-tile kt of both matrices into dbuf b: 8 global_load_lds / thread.
// Linear LDS dest (HW constraint), inverse-swizzled global source; ds_read
// applies the matching XOR (rule 21: both-sides-or-neither).
#define STAGE(b, kt)                                                          \
  do {                                                                        \
    _Pragma("unroll")                                                         \
    for (int _c = 0; _c < 4; ++_c) {                                          \
      size_t _col = (size_t)(kt) * 128 + scol[_c];                            \
      GLDS(Fb + abase + (size_t)srow[_c] * ND + _col, &ldsA[b][ldso[_c]]);    \
      GLDS(Pb + bbase + (size_t)srow[_c] * ND + _col, &ldsB[b][ldso[_c]]);    \
    }                                                                         \
  } while (0)

__global__ __launch_bounds__(256, 2)   // 2 blocks/CU: VGPR cap 256, LDS 2x64K
void gemm_loss_kernel(const unsigned char* __restrict__ Fb,
                      const unsigned char* __restrict__ Pb,
                      const float* __restrict__ f2, const float* __restrict__ p2,
                      const float* __restrict__ counts, const float* __restrict__ psum,
                      float* accum) {
  __shared__ __attribute__((aligned(16))) unsigned char ldsA[2][16384];
  __shared__ __attribute__((aligned(16))) unsigned char ldsB[2][16384];
  __shared__ float redI[4], redE[4];

  // XCD-bijective swizzle: 1024 wgs, 8 XCDs, 128 contiguous tiles each
  const int wg = (blockIdx.x & 7) * 128 + (blockIdx.x >> 3);
  const int bi = wg >> 5, bj = wg & 31;   // 32x32 tiles of 128x128

  const int tid = threadIdx.x;
  const int lane = tid & 63, wid = tid >> 6;
  const int wr = wid >> 1, wc = wid & 1;  // 2x2 wave grid, 64x64 each
  const int lo = lane & 15, hi = lane >> 4;

  // staging geometry: 1024 16-B chunks per matrix per kt, 4 per thread
  int srow[4], scol[4], ldso[4];
  #pragma unroll
  for (int c = 0; c < 4; ++c) {
    int idx = c * 256 + tid;
    srow[c] = idx >> 3;                          // row 0..127
    scol[c] = ((idx & 7) ^ (srow[c] & 7)) * 16;  // swizzled 16-B slot
    ldso[c] = idx * 16;
  }
  const size_t abase = (size_t)(bi * 128) * ND;
  const size_t bbase = (size_t)(bj * 128) * ND;

  f32x4 acc[4][4];
  f32x4 zero = {0.f, 0.f, 0.f, 0.f};
  #pragma unroll
  for (int m = 0; m < 4; ++m)
    #pragma unroll
    for (int n = 0; n < 4; ++n) acc[m][n] = zero;

  STAGE(0, 0);
  __syncthreads();   // vmcnt(0) drain + barrier (compiler-emitted)

  // 2-phase dbuf loop, compiler-scheduled: issue next-tile stage, then
  // 16 ds_read_b128 + 16 MFMA on current tile (compiler interleaves via
  // counted lgkmcnt), one vmcnt(0)+barrier per tile. Co-resident block
  // covers the drain.
  int cur = 0;
  #pragma unroll 1
  for (int kt = 0; kt < NT; ++kt) {
    if (kt + 1 < NT) STAGE(cur ^ 1, kt + 1);
    i32x8 av[4], bv[4];
    {
      const unsigned char* ab = &ldsA[cur][0];
      const unsigned char* bb = &ldsB[cur][0];
      #pragma unroll
      for (int m = 0; m < 4; ++m) {
        int r = wr * 64 + m * 16 + lo;
        int x = (r & 7) << 4;
        i32x4 l0 = *(const i32x4*)(ab + r * 128 + ((hi * 32) ^ x));
        i32x4 l1 = *(const i32x4*)(ab + r * 128 + ((hi * 32 + 16) ^ x));
        av[m] = __builtin_shufflevector(l0, l1, 0, 1, 2, 3, 4, 5, 6, 7);
      }
      #pragma unroll
      for (int n = 0; n < 4; ++n) {
        int r = wc * 64 + n * 16 + lo;
        int x = (r & 7) << 4;
        i32x4 l0 = *(const i32x4*)(bb + r * 128 + ((hi * 32) ^ x));
        i32x4 l1 = *(const i32x4*)(bb + r * 128 + ((hi * 32 + 16) ^ x));
        bv[n] = __builtin_shufflevector(l0, l1, 0, 1, 2, 3, 4, 5, 6, 7);
      }
    }
    __builtin_amdgcn_s_setprio(1);
    #pragma unroll
    for (int m = 0; m < 4; ++m)
      #pragma unroll
      for (int n = 0; n < 4; ++n)
        acc[m][n] = __builtin_amdgcn_mfma_scale_f32_16x16x128_f8f6f4(
            av[m], bv[n], acc[m][n], 0 /*A=fp8*/, 0 /*B=fp8*/,
            0, SCALE1, 0, SCALE1);
    __builtin_amdgcn_s_setprio(0);
    __syncthreads();   // vmcnt(0)+lgkmcnt(0)+barrier: next tile landed
    cur ^= 1;
  }

  // Epilogue: per-element msd -> intra (diag) / inter (off-diag) partials.
  // C/D layout (shape-determined): col = lane&15, row = (lane>>4)*4 + reg.
  float intra_l = 0.f, inter_l = 0.f;
  const int gi0 = bi * 128 + wr * 64 + hi * 4;
  const int gj0 = bj * 128 + wc * 64 + lo;
  float f2i[16];
  int mi[16];
  #pragma unroll
  for (int m = 0; m < 4; ++m)
    #pragma unroll
    for (int r = 0; r < 4; ++r) {
      int gi = gi0 + m * 16 + r;
      f2i[m * 4 + r] = f2[gi];
      mi[m * 4 + r] = counts[gi] > 0.f;
    }
  #pragma unroll
  for (int n = 0; n < 4; ++n) {
    int gj = gj0 + n * 16;
    float p2j = p2[gj];
    bool mj = psum[gj] != 0.f;
    if (mj) {
      #pragma unroll
      for (int m = 0; m < 4; ++m) {
        #pragma unroll
        for (int r = 0; r < 4; ++r) {
          if (!mi[m * 4 + r]) continue;
          int gi = gi0 + m * 16 + r;
          float cij = acc[m][n][r];
          float msd = fmaxf(f2i[m * 4 + r] + p2j - 2.f * cij, 0.f) * (1.f / 1024.f);
          if (gi == gj) {
            intra_l += msd;                 // diagonal: intra
          } else if (msd < 1.0f) {          // inter term nonzero only if sqrt(msd)<1
            float s = sqrtf(fmaxf(msd, 1e-12f));
            float e = 1.f - s;
            float e2 = e * e;
            inter_l += e2 * e2;             // (e/M)^2 * max(e,0)^2, M=1
          }
        }
      }
    }
  }
  #pragma unroll
  for (int off = 32; off; off >>= 1) {
    intra_l += __shfl_down(intra_l, off);
    inter_l += __shfl_down(inter_l, off);
  }
  if (lane == 0) { redI[wid] = intra_l; redE[wid] = inter_l; }
  __syncthreads();
  if (tid == 0) {
    atomicAdd(&accum[0], redI[0] + redI[1] + redI[2] + redI[3]);
    atomicAdd(&accum[1], redE[0] + redE[1] + redE[2] + redE[3]);
  }
}

// ---------------- mask counts + finalize (fused) ----------------
__global__ void finalize_kernel(const float* __restrict__ counts,
                                const float* __restrict__ psum,
                                const float* __restrict__ accum,
                                float* __restrict__ out) {
  int tid = threadIdx.x;
  int ni = 0, nj = 0, nd = 0;
  for (int i = tid; i < NC; i += 256) {
    int mi = counts[i] > 0.f;
    int mj = psum[i] != 0.f;
    ni += mi; nj += mj; nd += (mi & mj);
  }
  #pragma unroll
  for (int off = 32; off; off >>= 1) {
    ni += __shfl_down(ni, off);
    nj += __shfl_down(nj, off);
    nd += __shfl_down(nd, off);
  }
  __shared__ int r0[4], r1[4], r2[4];
  int wid = tid >> 6, lane = tid & 63;
  if (lane == 0) { r0[wid] = ni; r1[wid] = nj; r2[wid] = nd; }
  __syncthreads();
  if (tid == 0) {
    float fni = (float)(r0[0] + r0[1] + r0[2] + r0[3]);
    float fnj = (float)(r1[0] + r1[1] + r1[2] + r1[3]);
    float fnd = (float)(r2[0] + r2[1] + r2[2] + r2[3]);
    out[0] = accum[0] / (fnd + EPSF);
    out[1] = accum[1] / (fni * fnj - fnd + EPSF);
  }
}

extern "C" void kernel_launch(void* const* d_in, const int* in_sizes, int n_in,
                              void* d_out, int out_size, void* d_ws, size_t ws_size,
                              hipStream_t stream) {
  const float* F = (const float*)d_in[0];
  const float* P = (const float*)d_in[1];
  const int* ann = (const int*)d_in[2];
  int n_ann = in_sizes[2] / 5;

  char* ws = (char*)d_ws;
  unsigned char* Fb = (unsigned char*)ws;                          // 4 MB
  unsigned char* Pb = (unsigned char*)(ws + (size_t)NC * ND);      // 4 MB
  float* f2     = (float*)(ws + (size_t)NC * ND * 2);
  float* p2     = f2 + NC;
  float* psum   = p2 + NC;
  float* counts = psum + NC;
  float* accum  = counts + NC;  // [0]=intra_sum [1]=inter_sum

  float* out = (float*)d_out;

  convert_kernel<<<2 * NC + 1, 256, 0, stream>>>(F, P, Fb, Pb, f2, p2, psum,
                                                 ann, n_ann, counts, accum);
  gemm_loss_kernel<<<(NC / 128) * (NC / 128), 256, 0, stream>>>(Fb, Pb, f2, p2, counts, psum, accum);
  finalize_kernel<<<1, 256, 0, stream>>>(counts, psum, accum, out);
}

// Round 7
// 58.844 us; speedup vs baseline: 1.0677x; 1.0677x over previous
//
#include <hip/hip_runtime.h>
#include <hip/hip_bf16.h>

typedef float f32x4 __attribute__((ext_vector_type(4)));
typedef int   i32x4 __attribute__((ext_vector_type(4)));
typedef int   i32x8 __attribute__((ext_vector_type(8)));

#define NC 4096
#define ND 1024
#define EPSF 1e-10f
#define NT 8        // K-tiles of BK=128 (fp8)
#define SCALE1 127  // E8M0 exponent byte for 2^0

// ---------------- fp32 -> fp8 e4m3 convert + row norms/sums; last block = mask ----------------
__global__ void convert_kernel(const float* __restrict__ F, const float* __restrict__ P,
                               unsigned char* __restrict__ Fb, unsigned char* __restrict__ Pb,
                               float* __restrict__ f2, float* __restrict__ p2,
                               float* __restrict__ psum,
                               const int* __restrict__ ann, int n_ann,
                               float* __restrict__ counts, float* __restrict__ accum) {
  int bid = blockIdx.x;
  int tid = threadIdx.x;
  if (bid == 2 * NC) {  // fused mask/zero block (no atomics: LDS bitmap)
    __shared__ unsigned char mark[NC];
    for (int i = tid; i < NC; i += 256) mark[i] = 0;
    __syncthreads();
    for (int t = tid; t < n_ann; t += 256) {
      int idx = ann[t * 5 + 4];
      if (idx >= 0 && idx < NC) mark[idx] = 1;  // benign race: all write 1
    }
    __syncthreads();
    for (int i = tid; i < NC; i += 256) counts[i] = (float)mark[i];
    if (tid < 8) accum[tid] = 0.f;   // re-zero every call (graph replay)
    return;
  }
  bool isP = bid >= NC;
  int row = isP ? bid - NC : bid;
  const float* src = (isP ? P : F) + (size_t)row * ND;
  unsigned char* dst = (isP ? Pb : Fb) + (size_t)row * ND;
  float4 v = *reinterpret_cast<const float4*>(src + tid * 4);
  int pk = __builtin_amdgcn_cvt_pk_fp8_f32(v.x, v.y, 0, false);   // bytes 0,1
  pk = __builtin_amdgcn_cvt_pk_fp8_f32(v.z, v.w, pk, true);       // bytes 2,3
  *reinterpret_cast<int*>(dst + tid * 4) = pk;
  float sq = v.x * v.x + v.y * v.y + v.z * v.z + v.w * v.w;
  float sm = v.x + v.y + v.z + v.w;
  #pragma unroll
  for (int off = 32; off; off >>= 1) {
    sq += __shfl_down(sq, off);
    sm += __shfl_down(sm, off);
  }
  __shared__ float rs[4], rm[4];
  int wid = tid >> 6, lane = tid & 63;
  if (lane == 0) { rs[wid] = sq; rm[wid] = sm; }
  __syncthreads();
  if (tid == 0) {
    float tsq = rs[0] + rs[1] + rs[2] + rs[3];
    float tsm = rm[0] + rm[1] + rm[2] + rm[3];
    if (isP) { p2[row] = tsq; psum[row] = tsm; }
    else     { f2[row] = tsq; }
  }
}

// ---------------- fused 128x128 single-buffer MX-fp8 GEMM + loss reduction ----------------
#define GLDS(gsrc, ldst)                                                     \
  __builtin_amdgcn_global_load_lds(                                          \
      (__attribute__((address_space(1))) void*)(void*)(gsrc),                \
      (__attribute__((address_space(3))) void*)(void*)(ldst), 16, 0, 0)

#define FENCE() asm volatile("" ::: "memory")
#define BAR()  do { FENCE(); __builtin_amdgcn_s_barrier(); FENCE(); } while (0)
#define VMCNT0() asm volatile("s_waitcnt vmcnt(0)" ::: "memory")
#define LGKMCNT0() asm volatile("s_waitcnt lgkmcnt(0)" ::: "memory")

// Stage K-tile kt (A 16 KiB @ ldsbuf[0], B 16 KiB @ ldsbuf[16384]).
// 8 global_load_lds / thread. Linear LDS dest (HW constraint), inverse-
// swizzled global source; ds_read applies matching XOR (rule 21).
#define STAGE(kt)                                                             \
  do {                                                                        \
    _Pragma("unroll")                                                         \
    for (int _c = 0; _c < 4; ++_c) {                                          \
      size_t _col = (size_t)(kt) * 128 + scol[_c];                            \
      GLDS(Fb + abase + (size_t)srow[_c] * ND + _col, &ldsbuf[ldso[_c]]);     \
      GLDS(Pb + bbase + (size_t)srow[_c] * ND + _col,                         \
           &ldsbuf[16384 + ldso[_c]]);                                        \
    }                                                                         \
  } while (0)

__global__ __launch_bounds__(256, 3)   // 12 waves/CU: 3 blocks x 4 waves
void gemm_loss_kernel(const unsigned char* __restrict__ Fb,
                      const unsigned char* __restrict__ Pb,
                      const float* __restrict__ f2, const float* __restrict__ p2,
                      const float* __restrict__ counts, const float* __restrict__ psum,
                      float* accum) {
  __shared__ __attribute__((aligned(16))) unsigned char ldsbuf[32768];
  __shared__ float redI[4], redE[4];

  // 2-D slab XCD swizzle: 8 XCDs x (8 bi x 16 bj) slabs -> per-XCD working
  // set A 1 MB + B 2 MB = 3 MB < 4 MiB L2. Bijective on 1024 wgs.
  const int xcd = blockIdx.x & 7;
  const int s = blockIdx.x >> 3;                  // 0..127 within slab
  const int bi = (xcd >> 1) * 8 + (s >> 4);       // 4 slab-rows of 8
  const int bj = (xcd & 1) * 16 + (s & 15);       // 2 slab-cols of 16

  const int tid = threadIdx.x;
  const int lane = tid & 63, wid = tid >> 6;
  const int wr = wid >> 1, wc = wid & 1;  // 2x2 wave grid, 64x64 each
  const int lo = lane & 15, hi = lane >> 4;

  // staging geometry: 1024 16-B chunks per matrix per kt, 4 per thread
  int srow[4], scol[4], ldso[4];
  #pragma unroll
  for (int c = 0; c < 4; ++c) {
    int idx = c * 256 + tid;
    srow[c] = idx >> 3;                          // row 0..127
    scol[c] = ((idx & 7) ^ (srow[c] & 7)) * 16;  // swizzled 16-B slot
    ldso[c] = idx * 16;
  }
  const size_t abase = (size_t)(bi * 128) * ND;
  const size_t bbase = (size_t)(bj * 128) * ND;

  f32x4 acc[4][4];
  f32x4 zero = {0.f, 0.f, 0.f, 0.f};
  #pragma unroll
  for (int m = 0; m < 4; ++m)
    #pragma unroll
    for (int n = 0; n < 4; ++n) acc[m][n] = zero;

  STAGE(0);
  __syncthreads();   // prologue: vmcnt(0) drain + barrier (compiler-emitted)

  // Single-buffer K-loop (round-4 hazard order, fp8): all 16 frags -> regs,
  // lgkmcnt(0)+sched_barrier, BAR (all waves done reading), stage t+1 into
  // the SAME buffer, MFMA on regs, vmcnt(0), BAR (all DMAs landed).
  // 2 co-resident blocks execute through each drain.
  #pragma unroll 1
  for (int kt = 0; kt < NT; ++kt) {
    i32x8 av[4], bv[4];
    {
      const unsigned char* ab = &ldsbuf[0];
      const unsigned char* bb = &ldsbuf[16384];
      #pragma unroll
      for (int m = 0; m < 4; ++m) {
        int r = wr * 64 + m * 16 + lo;
        int x = (r & 7) << 4;
        i32x4 l0 = *(const i32x4*)(ab + r * 128 + ((hi * 32) ^ x));
        i32x4 l1 = *(const i32x4*)(ab + r * 128 + ((hi * 32 + 16) ^ x));
        av[m] = __builtin_shufflevector(l0, l1, 0, 1, 2, 3, 4, 5, 6, 7);
      }
      #pragma unroll
      for (int n = 0; n < 4; ++n) {
        int r = wc * 64 + n * 16 + lo;
        int x = (r & 7) << 4;
        i32x4 l0 = *(const i32x4*)(bb + r * 128 + ((hi * 32) ^ x));
        i32x4 l1 = *(const i32x4*)(bb + r * 128 + ((hi * 32 + 16) ^ x));
        bv[n] = __builtin_shufflevector(l0, l1, 0, 1, 2, 3, 4, 5, 6, 7);
      }
    }
    LGKMCNT0();                         // all 16 ds_reads complete
    __builtin_amdgcn_sched_barrier(0);  // rule 18: MFMA must not hoist above
    BAR();                              // every wave holds its regs
    if (kt + 1 < NT) STAGE(kt + 1);     // overwrite buffer (DMA, vmcnt)
    __builtin_amdgcn_s_setprio(1);
    #pragma unroll
    for (int m = 0; m < 4; ++m)
      #pragma unroll
      for (int n = 0; n < 4; ++n)
        acc[m][n] = __builtin_amdgcn_mfma_scale_f32_16x16x128_f8f6f4(
            av[m], bv[n], acc[m][n], 0 /*A=fp8*/, 0 /*B=fp8*/,
            0, SCALE1, 0, SCALE1);
    __builtin_amdgcn_s_setprio(0);
    VMCNT0();                           // this wave's 8 DMAs landed
    BAR();                              // all waves' DMAs landed
  }

  // Epilogue: per-element msd -> intra (diag) / inter (off-diag) partials.
  // C/D layout (shape-determined): col = lane&15, row = (lane>>4)*4 + reg.
  float intra_l = 0.f, inter_l = 0.f;
  const int gi0 = bi * 128 + wr * 64 + hi * 4;
  const int gj0 = bj * 128 + wc * 64 + lo;
  float f2i[16];
  int mi[16];
  #pragma unroll
  for (int m = 0; m < 4; ++m)
    #pragma unroll
    for (int r = 0; r < 4; ++r) {
      int gi = gi0 + m * 16 + r;
      f2i[m * 4 + r] = f2[gi];
      mi[m * 4 + r] = counts[gi] > 0.f;
    }
  #pragma unroll
  for (int n = 0; n < 4; ++n) {
    int gj = gj0 + n * 16;
    float p2j = p2[gj];
    bool mj = psum[gj] != 0.f;
    if (mj) {
      #pragma unroll
      for (int m = 0; m < 4; ++m) {
        #pragma unroll
        for (int r = 0; r < 4; ++r) {
          if (!mi[m * 4 + r]) continue;
          int gi = gi0 + m * 16 + r;
          float cij = acc[m][n][r];
          float msd = fmaxf(f2i[m * 4 + r] + p2j - 2.f * cij, 0.f) * (1.f / 1024.f);
          if (gi == gj) {
            intra_l += msd;                 // diagonal: intra
          } else if (msd < 1.0f) {          // inter term nonzero only if sqrt(msd)<1
            float s = sqrtf(fmaxf(msd, 1e-12f));
            float e = 1.f - s;
            float e2 = e * e;
            inter_l += e2 * e2;             // (e/M)^2 * max(e,0)^2, M=1
          }
        }
      }
    }
  }
  #pragma unroll
  for (int off = 32; off; off >>= 1) {
    intra_l += __shfl_down(intra_l, off);
    inter_l += __shfl_down(inter_l, off);
  }
  if (lane == 0) { redI[wid] = intra_l; redE[wid] = inter_l; }
  __syncthreads();
  if (tid == 0) {
    atomicAdd(&accum[0], redI[0] + redI[1] + redI[2] + redI[3]);
    atomicAdd(&accum[1], redE[0] + redE[1] + redE[2] + redE[3]);
  }
}

// ---------------- mask counts + finalize (fused) ----------------
__global__ void finalize_kernel(const float* __restrict__ counts,
                                const float* __restrict__ psum,
                                const float* __restrict__ accum,
                                float* __restrict__ out) {
  int tid = threadIdx.x;
  int ni = 0, nj = 0, nd = 0;
  for (int i = tid; i < NC; i += 256) {
    int mi = counts[i] > 0.f;
    int mj = psum[i] != 0.f;
    ni += mi; nj += mj; nd += (mi & mj);
  }
  #pragma unroll
  for (int off = 32; off; off >>= 1) {
    ni += __shfl_down(ni, off);
    nj += __shfl_down(nj, off);
    nd += __shfl_down(nd, off);
  }
  __shared__ int r0[4], r1[4], r2[4];
  int wid = tid >> 6, lane = tid & 63;
  if (lane == 0) { r0[wid] = ni; r1[wid] = nj; r2[wid] = nd; }
  __syncthreads();
  if (tid == 0) {
    float fni = (float)(r0[0] + r0[1] + r0[2] + r0[3]);
    float fnj = (float)(r1[0] + r1[1] + r1[2] + r1[3]);
    float fnd = (float)(r2[0] + r2[1] + r2[2] + r2[3]);
    out[0] = accum[0] / (fnd + EPSF);
    out[1] = accum[1] / (fni * fnj - fnd + EPSF);
  }
}

extern "C" void kernel_launch(void* const* d_in, const int* in_sizes, int n_in,
                              void* d_out, int out_size, void* d_ws, size_t ws_size,
                              hipStream_t stream) {
  const float* F = (const float*)d_in[0];
  const float* P = (const float*)d_in[1];
  const int* ann = (const int*)d_in[2];
  int n_ann = in_sizes[2] / 5;

  char* ws = (char*)d_ws;
  unsigned char* Fb = (unsigned char*)ws;                          // 4 MB
  unsigned char* Pb = (unsigned char*)(ws + (size_t)NC * ND);      // 4 MB
  float* f2     = (float*)(ws + (size_t)NC * ND * 2);
  float* p2     = f2 + NC;
  float* psum   = p2 + NC;
  float* counts = psum + NC;
  float* accum  = counts + NC;  // [0]=intra_sum [1]=inter_sum

  float* out = (float*)d_out;

  convert_kernel<<<2 * NC + 1, 256, 0, stream>>>(F, P, Fb, Pb, f2, p2, psum,
                                                 ann, n_ann, counts, accum);
  gemm_loss_kernel<<<(NC / 128) * (NC / 128), 256, 0, stream>>>(Fb, Pb, f2, p2, counts, psum, accum);
  finalize_kernel<<<1, 256, 0, stream>>>(counts, psum, accum, out);
}